// Round 2
// baseline (9585.847 us; speedup 1.0000x reference)
//
#include <hip/hip_runtime.h>

// LSTM T=32768, D=512, H=20.
// Phase 1: xg[t][80] = x[t] @ W_ih^T + (b_ih + b_hh)   (tiled fp32 GEMM)
// Phase 2: sequential scan, ONE wave, latency-optimized, FULLY HAND-UNROLLED:
//   lanes 0..19  : unit j, gates i (rowA=j)    and f (rowB=20+j)
//   lanes 32..51 : unit j, gates g (rowA=40+j) and o (rowB=60+j)
//   h broadcast via v_readlane -> SGPRs; dot product as 4 partial chains;
//   unified activation act(x) = C + A*rcp(1 + exp2(B*x)) so one exp2+rcp
//   pass covers sigmoid (lower half) and tanh (upper half) together.
//   All private arrays are accessed with compile-time-constant indices only
//   (macro unroll) so the compiler cannot demote them to scratch.
// Phase 3: out[t] = hs[t] @ W_out^T + b_out
//
// d_out layout: [0..T) outputs, [T..T+20) hT, [T+20..T+40) cT
// d_ws layout:  xg (T+16 rows x 80 fp32) then hs (T x 20 fp32)

#define TT 32768
#define DD 512
#define HH 20

__device__ __forceinline__ float ex2(float x) {
#if __has_builtin(__builtin_amdgcn_exp2f)
  return __builtin_amdgcn_exp2f(x);
#else
  return exp2f(x);
#endif
}
__device__ __forceinline__ float rcpa(float x) { return __builtin_amdgcn_rcpf(x); }
__device__ __forceinline__ float rlane(float v, int l) {
  return __int_as_float(__builtin_amdgcn_readlane(__float_as_int(v), l));
}

// ---------------- Phase 1: xg GEMM -------------------------------------
__global__ __launch_bounds__(256)
void xg_gemm(const float* __restrict__ x,    // (T, 512)
             const float* __restrict__ Wih,  // (80, 512)
             const float* __restrict__ bih,  // (80)
             const float* __restrict__ bhh,  // (80)
             float* __restrict__ xg)         // (T+16, 80)
{
  __shared__ float xa[64][68];
  __shared__ float wb[80][68];

  const int tid = threadIdx.x;
  const int t0  = blockIdx.x << 6;
  const int tt  = (tid & 15) << 2;
  const int gg  = (tid >> 4) * 5;

  float acc[4][5];
#pragma unroll
  for (int i = 0; i < 4; ++i)
#pragma unroll
    for (int q = 0; q < 5; ++q) acc[i][q] = 0.0f;

  for (int k0 = 0; k0 < DD; k0 += 64) {
#pragma unroll
    for (int i = 0; i < 4; ++i) {
      int id = tid + (i << 8);
      int r = id >> 4, c4 = (id & 15) << 2;
      *(float4*)&xa[r][c4] = *(const float4*)&x[(size_t)(t0 + r) * DD + k0 + c4];
    }
#pragma unroll
    for (int i = 0; i < 5; ++i) {
      int id = tid + (i << 8);
      int r = id >> 4, c4 = (id & 15) << 2;
      *(float4*)&wb[r][c4] = *(const float4*)&Wih[(size_t)r * DD + k0 + c4];
    }
    __syncthreads();

#pragma unroll 4
    for (int kk = 0; kk < 64; kk += 4) {
      float4 a[4], b[5];
#pragma unroll
      for (int i = 0; i < 4; ++i) a[i] = *(const float4*)&xa[tt + i][kk];
#pragma unroll
      for (int q = 0; q < 5; ++q) b[q] = *(const float4*)&wb[gg + q][kk];
#pragma unroll
      for (int i = 0; i < 4; ++i)
#pragma unroll
        for (int q = 0; q < 5; ++q) {
          acc[i][q] = fmaf(a[i].x, b[q].x, acc[i][q]);
          acc[i][q] = fmaf(a[i].y, b[q].y, acc[i][q]);
          acc[i][q] = fmaf(a[i].z, b[q].z, acc[i][q]);
          acc[i][q] = fmaf(a[i].w, b[q].w, acc[i][q]);
        }
    }
    __syncthreads();
  }

  float bg[5];
#pragma unroll
  for (int q = 0; q < 5; ++q) bg[q] = bih[gg + q] + bhh[gg + q];
#pragma unroll
  for (int i = 0; i < 4; ++i)
#pragma unroll
    for (int q = 0; q < 5; ++q)
      xg[(size_t)(t0 + tt + i) * 80 + gg + q] = acc[i][q] + bg[q];
}

// ---------------- Phase 2: sequential scan, one wave -------------------
__global__ __launch_bounds__(64, 1)
void lstm_scan(const float* __restrict__ xg,   // (T+16, 80)
               const float* __restrict__ Whh,  // (80, 20)
               const float* __restrict__ h0,   // (20)
               const float* __restrict__ c0,   // (20)
               float* __restrict__ hs,         // (T, 20)
               float* __restrict__ dout)       // d_out base (fp32)
{
  const int lane = threadIdx.x & 63;
  const int half = lane >> 5;
  int jj = lane & 31; if (jj > 19) jj = 19;
  const int rowA = half ? (40 + jj) : jj;   // i-row | g-row
  const int rowB = rowA + 20;               // f-row | o-row

  // Weights: 20+20 floats per lane, loaded as float4s, held in named-index regs.
  float wA[20], wB[20];
  {
    const float4* ra = (const float4*)(Whh + rowA * HH);  // 80B-aligned rows
    const float4* rb = (const float4*)(Whh + rowB * HH);
#define LDW(q) { float4 va = ra[q], vb = rb[q]; \
    wA[4*(q)+0]=va.x; wA[4*(q)+1]=va.y; wA[4*(q)+2]=va.z; wA[4*(q)+3]=va.w; \
    wB[4*(q)+0]=vb.x; wB[4*(q)+1]=vb.y; wB[4*(q)+2]=vb.z; wB[4*(q)+3]=vb.w; }
    LDW(0) LDW(1) LDW(2) LDW(3) LDW(4)
#undef LDW
  }

  const float A0 = half ? -2.0f        : 1.0f;
  const float B0 = half ? 2.88539008f  : -1.44269504f;
  const float C0 = half ? 1.0f         : 0.0f;

  float h = h0[jj];
  float c = c0[jj];

  // 8-step register prefetch ring, compile-time offsets only.
  float pA[8], pB[8];
  const float* pa = xg + rowA;
  const float* pb = xg + rowB;
#define PF(u) pA[u] = pa[(u) * 80]; pB[u] = pb[(u) * 80];
  PF(0) PF(1) PF(2) PF(3) PF(4) PF(5) PF(6) PF(7)
#undef PF
  pa += 8 * 80;   // prefetch base: row tb+8
  pb += 8 * 80;

  float* hsp = hs + (jj);   // lanes >= 20 masked off at store
  const bool live = (lane < HH);

  // one k-term: broadcast h_k to SGPR, two FMAs into rotating partials
#define MAC(K, A, B) { const float hk = rlane(h, K); \
    A = fmaf(hk, wA[K], A); B = fmaf(hk, wB[K], B); }

#define STEP(u) { \
    float gA = pA[u], gB = pB[u]; \
    pA[u] = pa[(u) * 80]; pB[u] = pb[(u) * 80]; \
    float a0 = gA, a1 = 0.f, a2 = 0.f, a3 = 0.f; \
    float b0 = gB, b1 = 0.f, b2 = 0.f, b3 = 0.f; \
    MAC( 0,a0,b0) MAC( 1,a1,b1) MAC( 2,a2,b2) MAC( 3,a3,b3) \
    MAC( 4,a0,b0) MAC( 5,a1,b1) MAC( 6,a2,b2) MAC( 7,a3,b3) \
    MAC( 8,a0,b0) MAC( 9,a1,b1) MAC(10,a2,b2) MAC(11,a3,b3) \
    MAC(12,a0,b0) MAC(13,a1,b1) MAC(14,a2,b2) MAC(15,a3,b3) \
    MAC(16,a0,b0) MAC(17,a1,b1) MAC(18,a2,b2) MAC(19,a3,b3) \
    gA = (a0 + a1) + (a2 + a3); \
    gB = (b0 + b1) + (b2 + b3); \
    const float vA = fmaf(A0, rcpa(1.0f + ex2(B0 * gA)), C0); \
    const float vB = rcpa(1.0f + ex2(-1.44269504f * gB)); \
    const float tg = __shfl(vA, (lane & 31) + 32); \
    const float so = __shfl(vB, (lane & 31) + 32); \
    c = fmaf(vB, c, vA * tg); \
    const float th = fmaf(-2.0f, rcpa(1.0f + ex2(2.88539008f * c)), 1.0f); \
    h = so * th; \
    if (live) hsp[(u) * HH] = h; \
  }

  for (int tb = 0; tb < TT; tb += 8) {
    STEP(0) STEP(1) STEP(2) STEP(3) STEP(4) STEP(5) STEP(6) STEP(7)
    pa += 8 * 80;
    pb += 8 * 80;
    hsp += 8 * HH;
  }
#undef STEP
#undef MAC

  if (live) {
    dout[TT + lane] = h;         // hT
    dout[TT + HH + lane] = c;    // cT
  }
}

// ---------------- Phase 3: output projection ---------------------------
__global__ __launch_bounds__(256)
void proj(const float* __restrict__ hs,    // (T, 20)
          const float* __restrict__ Wout,  // (1, 20)
          const float* __restrict__ bout,  // (1)
          float* __restrict__ out)         // (T)
{
  const int t = blockIdx.x * 256 + threadIdx.x;
  const float4* hp = (const float4*)(hs + (size_t)t * HH);
  float acc = bout[0];
#pragma unroll
  for (int q = 0; q < 5; ++q) {
    float4 hv = hp[q];
    float4 wv = *(const float4*)&Wout[q * 4];
    acc = fmaf(hv.x, wv.x, acc);
    acc = fmaf(hv.y, wv.y, acc);
    acc = fmaf(hv.z, wv.z, acc);
    acc = fmaf(hv.w, wv.w, acc);
  }
  out[t] = acc;
}

extern "C" void kernel_launch(void* const* d_in, const int* in_sizes, int n_in,
                              void* d_out, int out_size, void* d_ws, size_t ws_size,
                              hipStream_t stream) {
  const float* x    = (const float*)d_in[0];
  const float* h0   = (const float*)d_in[1];
  const float* c0   = (const float*)d_in[2];
  const float* Wih  = (const float*)d_in[3];
  const float* Whh  = (const float*)d_in[4];
  const float* bih  = (const float*)d_in[5];
  const float* bhh  = (const float*)d_in[6];
  const float* Wout = (const float*)d_in[7];
  const float* bout = (const float*)d_in[8];
  float* out = (float*)d_out;

  float* xg = (float*)d_ws;                       // (T+16) x 80
  float* hs = xg + (size_t)(TT + 16) * 80;        // T x 20

  xg_gemm<<<dim3(TT / 64), dim3(256), 0, stream>>>(x, Wih, bih, bhh, xg);
  lstm_scan<<<dim3(1), dim3(64), 0, stream>>>(xg, Whh, h0, c0, hs, out);
  proj<<<dim3(TT / 256), dim3(256), 0, stream>>>(hs, Wout, bout, out);
}

// Round 3
// 9071.050 us; speedup vs baseline: 1.0568x; 1.0568x over previous
//
#include <hip/hip_runtime.h>

// LSTM T=32768, D=512, H=20.
// Phase 1: xg[t][80] = x[t] @ W_ih^T + (b_ih + b_hh)   (tiled fp32 GEMM)
// Phase 2: sequential scan, ONE wave:
//   lanes 0..19  : unit j, gates i (rowA=j)    and f (rowB=20+j)
//   lanes 32..51 : unit j, gates g (rowA=40+j) and o (rowB=60+j)
//   - Whh rows laundered through inline asm so the RA cannot rematerialize
//     the invariant loads inside the loop (round-2 failure mode: VGPR=40,
//     40 global reloads per step).
//   - xg streamed via ping-pong register ring: 16 dword loads batched per
//     8-step phase, consumed one full phase (~2000 cy) later -> vmcnt slack.
//   - h broadcast via v_readlane -> SGPR operand of v_fma (1 SGPR/VALU ok).
//   - unified activation act(x) = C + A*rcp(1+exp2(B*x)): one exp2+rcp pass
//     covers sigmoid (lower half) and tanh (upper half).
// Phase 3: out[t] = hs[t] @ W_out^T + b_out
//
// d_out layout: [0..T) outputs, [T..T+20) hT, [T+20..T+40) cT
// d_ws layout:  xg (T+16 rows x 80 fp32) then hs (T x 20 fp32)

#define TT 32768
#define DD 512
#define HH 20

__device__ __forceinline__ float ex2(float x) {
#if __has_builtin(__builtin_amdgcn_exp2f)
  return __builtin_amdgcn_exp2f(x);
#else
  return exp2f(x);
#endif
}
__device__ __forceinline__ float rcpa(float x) { return __builtin_amdgcn_rcpf(x); }
__device__ __forceinline__ float rlane(float v, int l) {
  return __int_as_float(__builtin_amdgcn_readlane(__float_as_int(v), l));
}

// ---------------- Phase 1: xg GEMM -------------------------------------
__global__ __launch_bounds__(256)
void xg_gemm(const float* __restrict__ x,    // (T, 512)
             const float* __restrict__ Wih,  // (80, 512)
             const float* __restrict__ bih,  // (80)
             const float* __restrict__ bhh,  // (80)
             float* __restrict__ xg)         // (T+16, 80)
{
  __shared__ float xa[64][68];
  __shared__ float wb[80][68];

  const int tid = threadIdx.x;
  const int t0  = blockIdx.x << 6;
  const int tt  = (tid & 15) << 2;
  const int gg  = (tid >> 4) * 5;

  float acc[4][5];
#pragma unroll
  for (int i = 0; i < 4; ++i)
#pragma unroll
    for (int q = 0; q < 5; ++q) acc[i][q] = 0.0f;

  for (int k0 = 0; k0 < DD; k0 += 64) {
#pragma unroll
    for (int i = 0; i < 4; ++i) {
      int id = tid + (i << 8);
      int r = id >> 4, c4 = (id & 15) << 2;
      *(float4*)&xa[r][c4] = *(const float4*)&x[(size_t)(t0 + r) * DD + k0 + c4];
    }
#pragma unroll
    for (int i = 0; i < 5; ++i) {
      int id = tid + (i << 8);
      int r = id >> 4, c4 = (id & 15) << 2;
      *(float4*)&wb[r][c4] = *(const float4*)&Wih[(size_t)r * DD + k0 + c4];
    }
    __syncthreads();

#pragma unroll 4
    for (int kk = 0; kk < 64; kk += 4) {
      float4 a[4], b[5];
#pragma unroll
      for (int i = 0; i < 4; ++i) a[i] = *(const float4*)&xa[tt + i][kk];
#pragma unroll
      for (int q = 0; q < 5; ++q) b[q] = *(const float4*)&wb[gg + q][kk];
#pragma unroll
      for (int i = 0; i < 4; ++i)
#pragma unroll
        for (int q = 0; q < 5; ++q) {
          acc[i][q] = fmaf(a[i].x, b[q].x, acc[i][q]);
          acc[i][q] = fmaf(a[i].y, b[q].y, acc[i][q]);
          acc[i][q] = fmaf(a[i].z, b[q].z, acc[i][q]);
          acc[i][q] = fmaf(a[i].w, b[q].w, acc[i][q]);
        }
    }
    __syncthreads();
  }

  float bg[5];
#pragma unroll
  for (int q = 0; q < 5; ++q) bg[q] = bih[gg + q] + bhh[gg + q];
#pragma unroll
  for (int i = 0; i < 4; ++i)
#pragma unroll
    for (int q = 0; q < 5; ++q)
      xg[(size_t)(t0 + tt + i) * 80 + gg + q] = acc[i][q] + bg[q];
}

// ---------------- Phase 2: sequential scan, one wave -------------------
__global__ __launch_bounds__(64, 1)
void lstm_scan(const float* __restrict__ xg,   // (T+16, 80)
               const float* __restrict__ Whh,  // (80, 20)
               const float* __restrict__ h0,   // (20)
               const float* __restrict__ c0,   // (20)
               float* __restrict__ hs,         // (T, 20)
               float* __restrict__ dout)       // d_out base (fp32)
{
  const int lane = threadIdx.x & 63;
  const int half = lane >> 5;
  int jj = lane & 31; if (jj > 19) jj = 19;
  const int rowA = half ? (40 + jj) : jj;   // i-row | g-row
  const int rowB = rowA + 20;               // f-row | o-row

  // Weights: 20+20 floats per lane, float4 loads, then LAUNDERED through
  // inline asm so they are defined by a non-rematerializable op -> must
  // stay resident in VGPRs (fixes round-2 per-step reload).
  float wA[20], wB[20];
  {
    const float4* ra = (const float4*)(Whh + rowA * HH);
    const float4* rb = (const float4*)(Whh + rowB * HH);
#define LDW(q) { float4 va = ra[q], vb = rb[q]; \
    wA[4*(q)+0]=va.x; wA[4*(q)+1]=va.y; wA[4*(q)+2]=va.z; wA[4*(q)+3]=va.w; \
    wB[4*(q)+0]=vb.x; wB[4*(q)+1]=vb.y; wB[4*(q)+2]=vb.z; wB[4*(q)+3]=vb.w; }
    LDW(0) LDW(1) LDW(2) LDW(3) LDW(4)
#undef LDW
  }
#define LAU(K) asm("" : "+v"(wA[K])); asm("" : "+v"(wB[K]));
  LAU(0) LAU(1) LAU(2) LAU(3) LAU(4) LAU(5) LAU(6) LAU(7) LAU(8) LAU(9)
  LAU(10) LAU(11) LAU(12) LAU(13) LAU(14) LAU(15) LAU(16) LAU(17) LAU(18) LAU(19)
#undef LAU

  const float A0 = half ? -2.0f        : 1.0f;
  const float B0 = half ? 2.88539008f  : -1.44269504f;
  const float C0 = half ? 1.0f         : 0.0f;

  float h = h0[jj];
  float c = c0[jj];

  // Ping-pong register ring: 8 steps per phase, 16 dword loads per phase.
  float rA0[8], rB0[8], rA1[8], rB1[8];
  const float* pa = xg + rowA;
  const float* pb = xg + rowB;

#define LDRING(RA, RB) { \
    RA[0]=pa[0*80]; RB[0]=pb[0*80]; RA[1]=pa[1*80]; RB[1]=pb[1*80]; \
    RA[2]=pa[2*80]; RB[2]=pb[2*80]; RA[3]=pa[3*80]; RB[3]=pb[3*80]; \
    RA[4]=pa[4*80]; RB[4]=pb[4*80]; RA[5]=pa[5*80]; RB[5]=pb[5*80]; \
    RA[6]=pa[6*80]; RB[6]=pb[6*80]; RA[7]=pa[7*80]; RB[7]=pb[7*80]; \
    pa += 8*80; pb += 8*80; }

  LDRING(rA0, rB0)   // rows 0..7; pa/pb now at row 8

  float* hsp = hs + jj;
  const bool live = (lane < HH);

#define MAC(K, A, B) { const float hk = rlane(h, K); \
    A = fmaf(hk, wA[K], A); B = fmaf(hk, wB[K], B); }

#define STEP(RA, RB, u, HSOFF) { \
    float gA = RA[u], gB = RB[u]; \
    float a0 = gA, a1 = 0.f, a2 = 0.f, a3 = 0.f; \
    float b0 = gB, b1 = 0.f, b2 = 0.f, b3 = 0.f; \
    MAC( 0,a0,b0) MAC( 1,a1,b1) MAC( 2,a2,b2) MAC( 3,a3,b3) \
    MAC( 4,a0,b0) MAC( 5,a1,b1) MAC( 6,a2,b2) MAC( 7,a3,b3) \
    MAC( 8,a0,b0) MAC( 9,a1,b1) MAC(10,a2,b2) MAC(11,a3,b3) \
    MAC(12,a0,b0) MAC(13,a1,b1) MAC(14,a2,b2) MAC(15,a3,b3) \
    MAC(16,a0,b0) MAC(17,a1,b1) MAC(18,a2,b2) MAC(19,a3,b3) \
    gA = (a0 + a1) + (a2 + a3); \
    gB = (b0 + b1) + (b2 + b3); \
    const float vA = fmaf(A0, rcpa(1.0f + ex2(B0 * gA)), C0); \
    const float vB = rcpa(1.0f + ex2(-1.44269504f * gB)); \
    const float tg = __shfl(vA, (lane & 31) + 32); \
    const float so = __shfl(vB, (lane & 31) + 32); \
    c = fmaf(vB, c, vA * tg); \
    const float th = fmaf(-2.0f, rcpa(1.0f + ex2(2.88539008f * c)), 1.0f); \
    h = so * th; \
    if (live) hsp[(HSOFF) * HH] = h; \
  }

  for (int tb = 0; tb < TT; tb += 16) {
    LDRING(rA1, rB1)                    // rows tb+8 .. tb+15
    STEP(rA0, rB0, 0, 0) STEP(rA0, rB0, 1, 1)
    STEP(rA0, rB0, 2, 2) STEP(rA0, rB0, 3, 3)
    STEP(rA0, rB0, 4, 4) STEP(rA0, rB0, 5, 5)
    STEP(rA0, rB0, 6, 6) STEP(rA0, rB0, 7, 7)
    LDRING(rA0, rB0)                    // rows tb+16 .. tb+23 (xg padded to T+16)
    STEP(rA1, rB1, 0,  8) STEP(rA1, rB1, 1,  9)
    STEP(rA1, rB1, 2, 10) STEP(rA1, rB1, 3, 11)
    STEP(rA1, rB1, 4, 12) STEP(rA1, rB1, 5, 13)
    STEP(rA1, rB1, 6, 14) STEP(rA1, rB1, 7, 15)
    hsp += 16 * HH;
  }
#undef STEP
#undef MAC
#undef LDRING

  if (live) {
    dout[TT + lane] = h;         // hT
    dout[TT + HH + lane] = c;    // cT
  }
}

// ---------------- Phase 3: output projection ---------------------------
__global__ __launch_bounds__(256)
void proj(const float* __restrict__ hs,    // (T, 20)
          const float* __restrict__ Wout,  // (1, 20)
          const float* __restrict__ bout,  // (1)
          float* __restrict__ out)         // (T)
{
  const int t = blockIdx.x * 256 + threadIdx.x;
  const float4* hp = (const float4*)(hs + (size_t)t * HH);
  float acc = bout[0];
#pragma unroll
  for (int q = 0; q < 5; ++q) {
    float4 hv = hp[q];
    float4 wv = *(const float4*)&Wout[q * 4];
    acc = fmaf(hv.x, wv.x, acc);
    acc = fmaf(hv.y, wv.y, acc);
    acc = fmaf(hv.z, wv.z, acc);
    acc = fmaf(hv.w, wv.w, acc);
  }
  out[t] = acc;
}

extern "C" void kernel_launch(void* const* d_in, const int* in_sizes, int n_in,
                              void* d_out, int out_size, void* d_ws, size_t ws_size,
                              hipStream_t stream) {
  const float* x    = (const float*)d_in[0];
  const float* h0   = (const float*)d_in[1];
  const float* c0   = (const float*)d_in[2];
  const float* Wih  = (const float*)d_in[3];
  const float* Whh  = (const float*)d_in[4];
  const float* bih  = (const float*)d_in[5];
  const float* bhh  = (const float*)d_in[6];
  const float* Wout = (const float*)d_in[7];
  const float* bout = (const float*)d_in[8];
  float* out = (float*)d_out;

  float* xg = (float*)d_ws;                       // (T+16) x 80
  float* hs = xg + (size_t)(TT + 16) * 80;        // T x 20

  xg_gemm<<<dim3(TT / 64), dim3(256), 0, stream>>>(x, Wih, bih, bhh, xg);
  lstm_scan<<<dim3(1), dim3(64), 0, stream>>>(xg, Whh, h0, c0, hs, out);
  proj<<<dim3(TT / 256), dim3(256), 0, stream>>>(hs, Wout, bout, out);
}